// Round 10
// baseline (1008.044 us; speedup 1.0000x reference)
//
#include <hip/hip_runtime.h>

// np.float32(np.pi / 180)
#define PI180F 0.017453292519943295f

#define F_APPLY  1
#define F_RESET  2
#define F_UPD    4
#define F_BASEC0 8

// ---------------------------------------------------------------------------
// Rotation matrix, matching the reference's (Rz @ Ry) @ Rx in fp32.
// ---------------------------------------------------------------------------
__device__ __forceinline__ void compute_R(const float th[6], float R[9], float t[3]) {
    float ax = th[0] * PI180F, ay = th[1] * PI180F, az = th[2] * PI180F;
    float cx = cosf(ax), sx = sinf(ax);
    float cy = cosf(ay), sy = sinf(ay);
    float cz = cosf(az), sz = sinf(az);
    R[0] = cz * cy;  R[1] = (cz * sy) * sx - sz * cx;  R[2] = (cz * sy) * cx + sz * sx;
    R[3] = sz * cy;  R[4] = (sz * sy) * sx + cz * cx;  R[5] = (sz * sy) * cx - cz * sx;
    R[6] = -sy;      R[7] = cy * sx;                   R[8] = cy * cx;
    t[0] = th[3]; t[1] = th[4]; t[2] = th[5];
}

// ---------------------------------------------------------------------------
// Trilinear sample on a zero-padded volume (side P=D+3) — round-4 proven,
// branch-free, bit-identical to the predicated reference form.
// ---------------------------------------------------------------------------
template<int D>
__device__ __forceinline__ float tri_sample_pad(const float* __restrict__ vol,
                                                float c0, float c1, float c2) {
    constexpr int P = D + 3;
    float f0 = floorf(c0), f1 = floorf(c1), f2 = floorf(c2);
    int i0 = (int)f0, i1 = (int)f1, i2 = (int)f2;
    float t0 = c0 - f0, t1 = c1 - f1, t2 = c2 - f2;
    float w0[2] = {1.0f - t0, t0};
    float w1[2] = {1.0f - t1, t1};
    float w2[2] = {1.0f - t2, t2};
    int ip0 = ((unsigned)(i0 + 1) <= (unsigned)D) ? (i0 + 1) : (D + 1);
    int ip1 = ((unsigned)(i1 + 1) <= (unsigned)D) ? (i1 + 1) : (D + 1);
    int ip2 = ((unsigned)(i2 + 1) <= (unsigned)D) ? (i2 + 1) : (D + 1);
    const float* p = vol + ((ip0 * P + ip1) * P + ip2);
    float acc = 0.0f;
    acc += ((w0[0] * w1[0]) * w2[0]) * p[0];
    acc += ((w0[0] * w1[0]) * w2[1]) * p[1];
    acc += ((w0[0] * w1[1]) * w2[0]) * p[P];
    acc += ((w0[0] * w1[1]) * w2[1]) * p[P + 1];
    acc += ((w0[1] * w1[0]) * w2[0]) * p[P * P];
    acc += ((w0[1] * w1[0]) * w2[1]) * p[P * P + 1];
    acc += ((w0[1] * w1[1]) * w2[0]) * p[P * P + P];
    acc += ((w0[1] * w1[1]) * w2[1]) * p[P * P + P + 1];
    return acc;
}

// ---------------------------------------------------------------------------
// Eval body — linear voxel mapping (round-6 order) with EXACT hoisting:
// kk/x2 are per-thread loop-invariant (256 ≡ 0 mod D), ii/x0 hoisted to the
// plane loop. All hoisted values use identical expressions on identical
// inputs, and the per-thread v-order is unchanged → acc is bit-identical
// to rounds 6/9.
// ---------------------------------------------------------------------------
template<int D, int K>
__device__ __forceinline__ void eval_block(
    const float* __restrict__ srcp, const float* __restrict__ tgt,
    const float th[6], int b, int k, double* __restrict__ red)
{
    constexpr int logD = (D == 64) ? 6 : ((D == 32) ? 5 : 4);
    constexpr int n = D * D * D;
    constexpr int PS = (D + 3) * (D + 3) * (D + 3);
    constexpr int PLANES = D / K;             // ii-planes per block (K | D)
    constexpr int WITER = (D * D) / 256;      // 256-thread strips per plane
    static_assert(PLANES * K == D && WITER * 256 == D * D, "geometry");

    float R[9], t[3];
    compute_R(th, R, t);

    const float step = 2.0f / (float)(D - 1);
    const float scale = (float)(D - 1) * 0.5f;
    const float* s = srcp + (size_t)b * PS;
    const float* g = tgt + (size_t)b * n;
    const int tid = threadIdx.x;

    // per-thread invariants (identical expressions to the original path)
    const int kk = tid & (D - 1);
    const float x2 = -1.0f + (float)kk * step;

    double acc = 0.0;
    for (int ip = 0; ip < PLANES; ++ip) {
        const int ii = k * PLANES + ip;
        const float x0 = -1.0f + (float)ii * step;
        const float* gpl = g + ii * D * D;
#pragma unroll 4
        for (int w = 0; w < WITER; ++w) {
            int idx = w * 256 + tid;          // in-plane linear index
            int jj = idx >> logD;
            float x1 = -1.0f + (float)jj * step;
            float p0 = R[0] * x0 + R[1] * x1 + R[2] * x2 + t[0];
            float p1 = R[3] * x0 + R[4] * x1 + R[5] * x2 + t[1];
            float p2 = R[6] * x0 + R[7] * x1 + R[8] * x2 + t[2];
            float c0 = (p0 + 1.0f) * scale;
            float c1 = (p1 + 1.0f) * scale;
            float c2 = (p2 + 1.0f) * scale;
            float wv = tri_sample_pad<D>(s, c0, c1, c2);
            float d = wv - gpl[idx];
            acc += (double)(d * d);
        }
    }

    red[tid] = acc;
    __syncthreads();
#pragma unroll
    for (int st = 128; st > 0; st >>= 1) {
        if (tid < st) red[tid] += red[tid + st];
        __syncthreads();
    }
}

// ---------------------------------------------------------------------------
// Unified iteration kernel (redundant heads, kernel-boundary visibility):
//   Phase A (F_APPLY): accept/reject prev trial from pIn c0 (+F_RESET).
//   Phase B (F_UPD):   update1 — grad from pIn FD slots (+c0 base if
//                      F_BASEC0), momentum, direction, sttry.
//   Eval: configs c = cbase + (e>>3) at sttry (if UPD) else theta.
// Designated block ((e>>3)==0 && k==0) persists state (all double-buffered).
// ---------------------------------------------------------------------------
template<int D, int K>
__global__ __launch_bounds__(256) void opt_kernel(
    const float* __restrict__ srcp, const float* __restrict__ tgt,
    const float* __restrict__ thetaIn, const float* __restrict__ lcurIn,
    const int* __restrict__ activeIn,
    float* __restrict__ thetaOut, float* __restrict__ lcurOut,
    int* __restrict__ activeOut,
    float* __restrict__ lcurW,
    const float* __restrict__ momIn, float* __restrict__ momOut,
    const float* __restrict__ ttryIn, float* __restrict__ ttryOut,
    float* __restrict__ lall,
    const double* __restrict__ pIn, double* __restrict__ pOut,
    float ss, int cbase, int flags, int k3prev, int nprev)
{
    constexpr int n = D * D * D;
    __shared__ double red[256];
    __shared__ float lossf[13];
    __shared__ float sth[6], sttry[6];
    __shared__ float slcur;
    __shared__ int sact;

    const int tid = threadIdx.x;
    const int gb = blockIdx.x;
    const int k = gb % K;
    const int e = gb / K;
    const int b = e & 7;
    const int c = cbase + (e >> 3);
    const bool desig = ((e >> 3) == 0) && (k == 0);

    // ---- Phase A: apply previous trial decision / plain state load ----
    if (flags & F_APPLY) {
        if (tid < 32) {
            double v = 0.0;
            for (int i = tid; i < k3prev; i += 32) v += pIn[b * k3prev + i];
            v += __shfl_down(v, 16, 32);
            v += __shfl_down(v, 8, 32);
            v += __shfl_down(v, 4, 32);
            v += __shfl_down(v, 2, 32);
            v += __shfl_down(v, 1, 32);
            if (tid == 0) {
                int na = activeIn[b];
                float l = lcurIn[b];
                float th[6];
#pragma unroll
                for (int j = 0; j < 6; ++j) th[j] = thetaIn[b * 6 + j];
                if (na) {
                    float ln = (float)(v / (double)nprev);
                    if (ln + 1e-4f < l) {
#pragma unroll
                        for (int j = 0; j < 6; ++j) th[j] = ttryIn[b * 6 + j];
                        l = ln;
                    } else {
                        na = 0;
                    }
                }
                if (flags & F_RESET) na = 1;
#pragma unroll
                for (int j = 0; j < 6; ++j) sth[j] = th[j];
                sact = na;
                slcur = l;
                if (desig) {
#pragma unroll
                    for (int j = 0; j < 6; ++j) thetaOut[b * 6 + j] = th[j];
                    lcurOut[b] = l;
                    activeOut[b] = na;
                }
            }
        }
    } else {
        if (tid < 6) sth[tid] = thetaIn[b * 6 + tid];
        if (tid == 0) { sact = activeIn[b]; slcur = lcurIn[b]; }
    }
    __syncthreads();

    // ---- Phase B: update1 (grad/momentum/direction/ttry) ----
    if (flags & F_UPD) {
        if (sact) {
            const bool bc0 = (flags & F_BASEC0) != 0;
            const int nsl = bc0 ? 13 : 12;
#pragma unroll
            for (int p = 0; p < 2; ++p) {
                int ci = p * 8 + (tid >> 5);
                if (ci < nsl) {
                    int ca = bc0 ? ci : ci + 1;
                    int kk = tid & 31;
                    double v = 0.0;
                    for (int i = kk; i < K; i += 32) v += pIn[(size_t)(ca * 8 + b) * K + i];
                    v += __shfl_down(v, 16, 32);
                    v += __shfl_down(v, 8, 32);
                    v += __shfl_down(v, 4, 32);
                    v += __shfl_down(v, 2, 32);
                    v += __shfl_down(v, 1, 32);
                    if (kk == 0) lossf[ca] = (float)(v / (double)n);
                }
            }
            __syncthreads();
            if (tid == 0) {
                float lb = bc0 ? lossf[0] : slcur;
                float ub[6];
#pragma unroll
                for (int j = 0; j < 6; ++j) {
                    float grad = lossf[1 + j] - lossf[7 + j];
                    float u = bc0 ? grad : (momIn[b * 6 + j] * 0.1f + grad);
                    ub[j] = u;
                }
                float ss2 = 0.0f;
#pragma unroll
                for (int j = 0; j < 6; ++j) ss2 += ub[j] * ub[j];
                float denom = sqrtf(ss2) + 1e-6f;
#pragma unroll
                for (int j = 0; j < 6; ++j) sttry[j] = sth[j] - ss * (ub[j] / denom);
                if (desig) {
                    lall[b] = lb;
                    if (bc0) lcurW[b] = lb;
#pragma unroll
                    for (int j = 0; j < 6; ++j) momOut[b * 6 + j] = ub[j];
#pragma unroll
                    for (int j = 0; j < 6; ++j) ttryOut[b * 6 + j] = sttry[j];
                }
            }
        } else {
            if (desig && tid < 6) momOut[b * 6 + tid] = momIn[b * 6 + tid];
        }
        __syncthreads();
    }

    if (!sact) return;

    // ---- Eval ----
    float evth[6];
#pragma unroll
    for (int j = 0; j < 6; ++j) evth[j] = (flags & F_UPD) ? sttry[j] : sth[j];
    if (c > 0) {
        int j = (c - 1) % 6;
        evth[j] += (c <= 6) ? ss : -ss;
    }
    eval_block<D, K>(srcp, tgt, evth, b, k, red);
    if (tid == 0) pOut[(size_t)(c * 8 + b) * K + k] = red[0];
}

// ---------------------------------------------------------------------------
// Finalize: applies the very last trial decision (level 2, K=32, n=262144)
// and writes theta-out + loss.
// ---------------------------------------------------------------------------
__global__ __launch_bounds__(256) void finalize_kernel(
    const float* __restrict__ theta0,
    const float* __restrict__ theta, const float* __restrict__ lcur,
    const int* __restrict__ active, const float* __restrict__ ttry,
    const double* __restrict__ pB, const float* __restrict__ lall,
    float* __restrict__ out)
{
    __shared__ double rs[8];
    __shared__ float fth[48];
    const int tid = threadIdx.x;
    const int r = tid >> 5, l = tid & 31;
    {
        double v = pB[r * 32 + l];
        v += __shfl_down(v, 16, 32);
        v += __shfl_down(v, 8, 32);
        v += __shfl_down(v, 4, 32);
        v += __shfl_down(v, 2, 32);
        v += __shfl_down(v, 1, 32);
        if (l == 0) rs[r] = v;
    }
    __syncthreads();
    if (tid < 8) {
        int b = tid;
        bool acc = false;
        if (active[b]) {
            float ln = (float)(rs[b] / 262144.0);
            acc = (ln + 1e-4f < lcur[b]);
        }
        for (int j = 0; j < 6; ++j)
            fth[b * 6 + j] = acc ? ttry[b * 6 + j] : theta[b * 6 + j];
    }
    __syncthreads();
    if (tid < 48) {
        int j = tid % 6;
        float d2r = (j < 3) ? PI180F : 1.0f;
        float td = fth[tid] * d2r;
        out[tid] = theta0[tid] + (td - theta0[tid]);
    } else if (tid < 56) {
        out[tid] = lall[tid - 48];
    }
}

// ---------------------------------------------------------------------------
// Pool into padded src layout (borders written as zero — no memset needed)
// + linear tgt pool. Accumulation order identical to rounds 4-9.
// ---------------------------------------------------------------------------
template<int f>
__global__ void pool_pad_kernel(const float* __restrict__ src, const float* __restrict__ tgt,
                                float* __restrict__ srcp, float* __restrict__ tgtp)
{
    constexpr int Do = 64 / f;
    constexpr int P = Do + 3;
    constexpr int nPad = 8 * P * P * P;
    constexpr int nLin = 8 * Do * Do * Do;
    int idx = blockIdx.x * blockDim.x + threadIdx.x;
    if (idx < nPad) {
        int kk = idx % P;
        int jj = (idx / P) % P;
        int ii = (idx / (P * P)) % P;
        int b  = idx / (P * P * P);
        float val = 0.0f;
        if (ii >= 1 && ii <= Do && jj >= 1 && jj <= Do && kk >= 1 && kk <= Do) {
            const float* v = src + (size_t)b * 262144;
            int i0 = ii - 1, j0 = jj - 1, k0 = kk - 1;
            double s = 0.0;
            for (int p = 0; p < f; ++p)
                for (int q = 0; q < f; ++q)
                    for (int r = 0; r < f; ++r)
                        s += (double)v[((i0 * f + p) * 64 + (j0 * f + q)) * 64 + (k0 * f + r)];
            val = (float)(s / (double)(f * f * f));
        }
        srcp[idx] = val;
    } else if (idx < nPad + nLin) {
        int id = idx - nPad;
        int kk = id % Do;
        int jj = (id / Do) % Do;
        int ii = (id / (Do * Do)) % Do;
        int b  = id / (Do * Do * Do);
        const float* v = tgt + (size_t)b * 262144;
        double s = 0.0;
        for (int p = 0; p < f; ++p)
            for (int q = 0; q < f; ++q)
                for (int r = 0; r < f; ++r)
                    s += (double)v[((ii * f + p) * 64 + (jj * f + q)) * 64 + (kk * f + r)];
        tgtp[id] = (float)(s / (double)(f * f * f));
    }
}

// Copy D=64 src into padded layout (P=67), borders zero.
__global__ void pad_copy_kernel(const float* __restrict__ src, float* __restrict__ dst)
{
    int idx = blockIdx.x * blockDim.x + threadIdx.x;
    if (idx >= 8 * 67 * 67 * 67) return;
    int kk = idx % 67;
    int jj = (idx / 67) % 67;
    int ii = (idx / (67 * 67)) % 67;
    int b  = idx / (67 * 67 * 67);
    float v = 0.0f;
    if (ii >= 1 && ii <= 64 && jj >= 1 && jj <= 64 && kk >= 1 && kk <= 64)
        v = src[(((size_t)b * 64 + (ii - 1)) * 64 + (jj - 1)) * 64 + (kk - 1)];
    dst[idx] = v;
}

__global__ void init_kernel(const float* __restrict__ theta_in,
                            float* __restrict__ theta_deg,
                            float* __restrict__ lcur,
                            int* __restrict__ active)
{
    int t = threadIdx.x;
    if (t < 48) {
        int j = t % 6;
        float d2r = (j < 3) ? PI180F : 1.0f;
        theta_deg[t] = theta_in[t] / d2r;
    }
    if (t < 8) { active[t] = 1; lcur[t] = 0.0f; }
}

// ---------------------------------------------------------------------------
struct Bufs {
    float *thetaS[2], *lcurS[2], *momS[2], *ttryS[2];
    int   *activeS[2];
    float *lall;
    double *P[2];
};

template<int D, int K>
static void run_level(const float* srcp, const float* tgt, Bufs& bf,
                      int& scur, int& mcur, int& tcur, int& pcur,
                      int k3prevLvl, int nprevLvl, float ss0, bool veryFirst,
                      hipStream_t stream)
{
    constexpr int n = D * D * D;
    float ssv = ss0;
    for (int s = 0; s < 4; ++s) {
        // ---- S kernel (step start) ----
        {
            int flags = F_RESET | ((veryFirst && s == 0) ? 0 : F_APPLY);
            int cb    = (s == 0) ? 0 : 1;
            int nconf = (s == 0) ? 13 : 12;
            int k3p   = (s == 0) ? k3prevLvl : K;
            int np    = (s == 0) ? nprevLvl  : n;
            opt_kernel<D, K><<<nconf * 8 * K, 256, 0, stream>>>(
                srcp, tgt,
                bf.thetaS[scur], bf.lcurS[scur], bf.activeS[scur],
                bf.thetaS[scur ^ 1], bf.lcurS[scur ^ 1], bf.activeS[scur ^ 1],
                bf.lcurS[scur],
                bf.momS[mcur], bf.momS[mcur ^ 1],
                bf.ttryS[tcur], bf.ttryS[tcur ^ 1],
                bf.lall, bf.P[pcur], bf.P[pcur ^ 1],
                ssv, cb, flags, k3p, np);
            if (flags & F_APPLY) scur ^= 1;
            pcur ^= 1;
        }
        // ---- M kernels j=1..10 ----
        for (int j = 1; j <= 10; ++j) {
            int flags = F_UPD | ((j == 1) ? ((s == 0) ? F_BASEC0 : 0) : F_APPLY);
            int nconf = (j == 10) ? 1 : 13;
            opt_kernel<D, K><<<nconf * 8 * K, 256, 0, stream>>>(
                srcp, tgt,
                bf.thetaS[scur], bf.lcurS[scur], bf.activeS[scur],
                bf.thetaS[scur ^ 1], bf.lcurS[scur ^ 1], bf.activeS[scur ^ 1],
                bf.lcurS[scur],
                bf.momS[mcur], bf.momS[mcur ^ 1],
                bf.ttryS[tcur], bf.ttryS[tcur ^ 1],
                bf.lall, bf.P[pcur], bf.P[pcur ^ 1],
                ssv, 0, flags, K, n);
            if (flags & F_APPLY) scur ^= 1;
            mcur ^= 1; tcur ^= 1; pcur ^= 1;
        }
        ssv *= 0.5f;
    }
}

extern "C" void kernel_launch(void* const* d_in, const int* in_sizes, int n_in,
                              void* d_out, int out_size, void* d_ws, size_t ws_size,
                              hipStream_t stream)
{
    const float* theta0 = (const float*)d_in[0];
    const float* source = (const float*)d_in[1];
    const float* target = (const float*)d_in[2];
    float* out = (float*)d_out;

    char* ws = (char*)d_ws;
    size_t off = 0;
    auto alloc = [&](size_t bytes) -> void* {
        off = (off + 255) & ~(size_t)255;
        void* p = ws + off;
        off += bytes;
        return p;
    };
    Bufs bf;
    for (int i = 0; i < 2; ++i) {
        bf.thetaS[i]  = (float*)alloc(48 * 4);
        bf.lcurS[i]   = (float*)alloc(8 * 4);
        bf.activeS[i] = (int*)alloc(8 * 4);
        bf.momS[i]    = (float*)alloc(48 * 4);
        bf.ttryS[i]   = (float*)alloc(48 * 4);
        bf.P[i]       = (double*)alloc(13 * 8 * 32 * 8);
    }
    bf.lall = (float*)alloc(8 * 4);
    float* tgt2  = (float*)alloc((size_t)8 * 32768 * 4);
    float* tgt4  = (float*)alloc((size_t)8 * 4096 * 4);
    const size_t PS16 = 19 * 19 * 19, PS32 = 35 * 35 * 35, PS64 = 67 * 67 * 67;
    float* pad16 = (float*)alloc((size_t)8 * PS16 * 4);
    float* pad32 = (float*)alloc((size_t)8 * PS32 * 4);
    float* pad64 = (float*)alloc((size_t)8 * PS64 * 4);

    pool_pad_kernel<2><<<(int)((8 * PS32 + 8 * 32768 + 255) / 256), 256, 0, stream>>>(
        source, target, pad32, tgt2);
    pool_pad_kernel<4><<<(int)((8 * PS16 + 8 * 4096 + 255) / 256), 256, 0, stream>>>(
        source, target, pad16, tgt4);
    pad_copy_kernel<<<(int)((8 * PS64 + 255) / 256), 256, 0, stream>>>(source, pad64);
    init_kernel<<<1, 64, 0, stream>>>(theta0, bf.thetaS[0], bf.lcurS[0], bf.activeS[0]);

    int scur = 0, mcur = 0, tcur = 0, pcur = 0;
    run_level<16,  2>(pad16, tgt4,   bf, scur, mcur, tcur, pcur,  1,     1, 8.0f, true,  stream);
    run_level<32,  8>(pad32, tgt2,   bf, scur, mcur, tcur, pcur,  2,  4096, 4.0f, false, stream);
    run_level<64, 32>(pad64, target, bf, scur, mcur, tcur, pcur,  8, 32768, 2.0f, false, stream);

    finalize_kernel<<<1, 256, 0, stream>>>(
        theta0, bf.thetaS[scur], bf.lcurS[scur], bf.activeS[scur],
        bf.ttryS[tcur], bf.P[pcur], bf.lall, out);
}

// Round 11
// 963.358 us; speedup vs baseline: 1.0464x; 1.0464x over previous
//
#include <hip/hip_runtime.h>

// np.float32(np.pi / 180)
#define PI180F 0.017453292519943295f

// ---------------------------------------------------------------------------
// Rotation matrix, matching the reference's (Rz @ Ry) @ Rx in fp32.
// ---------------------------------------------------------------------------
__device__ __forceinline__ void compute_R(const float th[6], float R[9], float t[3]) {
    float ax = th[0] * PI180F, ay = th[1] * PI180F, az = th[2] * PI180F;
    float cx = cosf(ax), sx = sinf(ax);
    float cy = cosf(ay), sy = sinf(ay);
    float cz = cosf(az), sz = sinf(az);
    R[0] = cz * cy;  R[1] = (cz * sy) * sx - sz * cx;  R[2] = (cz * sy) * cx + sz * sx;
    R[3] = sz * cy;  R[4] = (sz * sy) * sx + cz * cx;  R[5] = (sz * sy) * cx - cz * sx;
    R[6] = -sy;      R[7] = cy * sx;                   R[8] = cy * cx;
    t[0] = th[3]; t[1] = th[4]; t[2] = th[5];
}

// ---------------------------------------------------------------------------
// Trilinear sample on a zero-padded volume (side P=D+3) — round-4 proven,
// branch-free, bit-identical to the predicated reference form.
// ---------------------------------------------------------------------------
template<int D>
__device__ __forceinline__ float tri_sample_pad(const float* __restrict__ vol,
                                                float c0, float c1, float c2) {
    constexpr int P = D + 3;
    float f0 = floorf(c0), f1 = floorf(c1), f2 = floorf(c2);
    int i0 = (int)f0, i1 = (int)f1, i2 = (int)f2;
    float t0 = c0 - f0, t1 = c1 - f1, t2 = c2 - f2;
    float w0[2] = {1.0f - t0, t0};
    float w1[2] = {1.0f - t1, t1};
    float w2[2] = {1.0f - t2, t2};
    int ip0 = ((unsigned)(i0 + 1) <= (unsigned)D) ? (i0 + 1) : (D + 1);
    int ip1 = ((unsigned)(i1 + 1) <= (unsigned)D) ? (i1 + 1) : (D + 1);
    int ip2 = ((unsigned)(i2 + 1) <= (unsigned)D) ? (i2 + 1) : (D + 1);
    const float* p = vol + ((ip0 * P + ip1) * P + ip2);
    float acc = 0.0f;
    acc += ((w0[0] * w1[0]) * w2[0]) * p[0];
    acc += ((w0[0] * w1[0]) * w2[1]) * p[1];
    acc += ((w0[0] * w1[1]) * w2[0]) * p[P];
    acc += ((w0[0] * w1[1]) * w2[1]) * p[P + 1];
    acc += ((w0[1] * w1[0]) * w2[0]) * p[P * P];
    acc += ((w0[1] * w1[0]) * w2[1]) * p[P * P + 1];
    acc += ((w0[1] * w1[1]) * w2[0]) * p[P * P + P];
    acc += ((w0[1] * w1[1]) * w2[1]) * p[P * P + P + 1];
    return acc;
}

// ---------------------------------------------------------------------------
// Eval body — ROUND-6 VERBATIM inner loop (linear voxel mapping; empirical
// best). Reduction tail: wave64 shuffle butterfly + single barrier (fp64
// order change only — proven absmax-invariant).
// ---------------------------------------------------------------------------
template<int D, int K>
__device__ __forceinline__ void eval_block(
    const float* __restrict__ srcp, const float* __restrict__ tgt,
    const float th[6], int b, int k, double* __restrict__ red)
{
    constexpr int logD = (D == 64) ? 6 : ((D == 32) ? 5 : 4);
    constexpr int n = D * D * D;
    constexpr int PS = (D + 3) * (D + 3) * (D + 3);
    float R[9], t[3];
    compute_R(th, R, t);

    constexpr int chunk = n / K;
    const int vstart = k * chunk;
    const int vend = vstart + chunk;
    const float step = 2.0f / (float)(D - 1);
    const float scale = (float)(D - 1) * 0.5f;
    const float* s = srcp + (size_t)b * PS;
    const float* g = tgt + (size_t)b * n;

    double acc = 0.0;
    for (int v = vstart + threadIdx.x; v < vend; v += 256) {
        int kk = v & (D - 1);
        int jj = (v >> logD) & (D - 1);
        int ii = v >> (2 * logD);
        float x0 = -1.0f + (float)ii * step;
        float x1 = -1.0f + (float)jj * step;
        float x2 = -1.0f + (float)kk * step;
        float p0 = R[0] * x0 + R[1] * x1 + R[2] * x2 + t[0];
        float p1 = R[3] * x0 + R[4] * x1 + R[5] * x2 + t[1];
        float p2 = R[6] * x0 + R[7] * x1 + R[8] * x2 + t[2];
        float c0 = (p0 + 1.0f) * scale;
        float c1 = (p1 + 1.0f) * scale;
        float c2 = (p2 + 1.0f) * scale;
        float w = tri_sample_pad<D>(s, c0, c1, c2);
        float d = w - g[v];
        acc += (double)(d * d);
    }

    // wave64 butterfly, then 4 wave sums via LDS, one barrier total
    acc += __shfl_down(acc, 32);
    acc += __shfl_down(acc, 16);
    acc += __shfl_down(acc, 8);
    acc += __shfl_down(acc, 4);
    acc += __shfl_down(acc, 2);
    acc += __shfl_down(acc, 1);
    if ((threadIdx.x & 63) == 0) red[threadIdx.x >> 6] = acc;
    __syncthreads();
    if (threadIdx.x == 0) red[0] = ((red[0] + red[1]) + red[2]) + red[3];
}

// ---------------------------------------------------------------------------
// FD eval with redundant update2 head (round-6 structure verbatim).
// ---------------------------------------------------------------------------
template<int D, int K>
__global__ __launch_bounds__(256) void fd_kernel(
    const float* __restrict__ srcp, const float* __restrict__ tgt,
    const float* __restrict__ thetaIn, const float* __restrict__ lcurIn,
    const int* __restrict__ activeIn,
    float* __restrict__ thetaOut, float* __restrict__ lcurOut,
    int* __restrict__ activeOut,
    const float* __restrict__ ttry, const double* __restrict__ pB,
    double* __restrict__ partials,
    float ss, int first, int apply, int reset, int k3prev, int nprev)
{
    __shared__ double red[256];
    __shared__ float sth[6];
    __shared__ int sact;
    const int tid = threadIdx.x;
    const int gb = blockIdx.x;
    const int k = gb % K;
    const int e = gb / K;
    const int b = e & 7;
    const int c = first ? (e >> 3) : (e >> 3) + 1;

    if (apply) {
        if (tid < 32) {
            double v = (tid < k3prev) ? pB[b * k3prev + tid] : 0.0;
            v += __shfl_down(v, 16, 32);
            v += __shfl_down(v, 8, 32);
            v += __shfl_down(v, 4, 32);
            v += __shfl_down(v, 2, 32);
            v += __shfl_down(v, 1, 32);
            if (tid == 0) {
                int na = activeIn[b];
                float l = lcurIn[b];
                float th[6];
#pragma unroll
                for (int j = 0; j < 6; ++j) th[j] = thetaIn[b * 6 + j];
                if (na) {
                    float ln = (float)(v / (double)nprev);
                    if (ln + 1e-4f < l) {
#pragma unroll
                        for (int j = 0; j < 6; ++j) th[j] = ttry[b * 6 + j];
                        l = ln;
                    } else {
                        na = 0;
                    }
                }
                if (reset) na = 1;
#pragma unroll
                for (int j = 0; j < 6; ++j) sth[j] = th[j];
                sact = na;
                if (((e >> 3) == 0) && (k == 0)) {
#pragma unroll
                    for (int j = 0; j < 6; ++j) thetaOut[b * 6 + j] = th[j];
                    lcurOut[b] = l;
                    activeOut[b] = na;
                }
            }
        }
        __syncthreads();
    } else {
        if (tid < 6) sth[tid] = thetaIn[b * 6 + tid];
        if (tid == 0) sact = activeIn[b];
        __syncthreads();
    }

    if (!sact) return;
    float th[6];
#pragma unroll
    for (int j = 0; j < 6; ++j) th[j] = sth[j];
    if (c > 0) {
        int j = (c - 1) % 6;
        th[j] += (c <= 6) ? ss : -ss;
    }
    eval_block<D, K>(srcp, tgt, th, b, k, red);
    if (tid == 0) partials[(size_t)(c * 8 + b) * K + k] = red[0];
}

// ---------------------------------------------------------------------------
// Trial eval with redundant update1 head (round-6 structure verbatim).
// ---------------------------------------------------------------------------
template<int D, int K3, int K>
__global__ __launch_bounds__(256) void trial_kernel(
    const float* __restrict__ srcp, const float* __restrict__ tgt,
    const float* __restrict__ theta, float* __restrict__ lcur,
    const int* __restrict__ active,
    const float* __restrict__ momIn, float* __restrict__ momOut,
    float* __restrict__ ttry, float* __restrict__ lall,
    const double* __restrict__ pA, double* __restrict__ pB,
    float ss, int first)
{
    constexpr int n = D * D * D;
    __shared__ double red[256];
    __shared__ float lossf[13];
    __shared__ float sttry[6];
    const int tid = threadIdx.x;
    const int gb = blockIdx.x;
    const int k = gb % K3;
    const int b = gb / K3;

    if (!active[b]) {
        // momentum copy-through (reference: buf unchanged where inactive)
        if (k == 0 && tid < 6) momOut[b * 6 + tid] = momIn[b * 6 + tid];
        return;
    }

    const int nconf = first ? 13 : 12;
#pragma unroll
    for (int p = 0; p < 2; ++p) {
        int ci = p * 8 + (tid >> 5);            // group of 32 lanes per slot
        if (ci < nconf) {
            int ca = first ? ci : ci + 1;       // absolute config index
            int kk = tid & 31;
            double v = (kk < K) ? pA[(size_t)(ca * 8 + b) * K + kk] : 0.0;
            v += __shfl_down(v, 16, 32);
            v += __shfl_down(v, 8, 32);
            v += __shfl_down(v, 4, 32);
            v += __shfl_down(v, 2, 32);
            v += __shfl_down(v, 1, 32);
            if (kk == 0) lossf[ca] = (float)(v / (double)n);
        }
    }
    __syncthreads();
    if (tid == 0) {
        float lb = first ? lossf[0] : lcur[b];
        float ub[6];
#pragma unroll
        for (int j = 0; j < 6; ++j) {
            float grad = lossf[1 + j] - lossf[7 + j];
            float u = first ? grad : (momIn[b * 6 + j] * 0.1f + grad);
            ub[j] = u;
        }
        float ss2 = 0.0f;
#pragma unroll
        for (int j = 0; j < 6; ++j) ss2 += ub[j] * ub[j];
        float denom = sqrtf(ss2) + 1e-6f;
#pragma unroll
        for (int j = 0; j < 6; ++j) sttry[j] = theta[b * 6 + j] - ss * (ub[j] / denom);
        if (k == 0) {
            lall[b] = lb;
            if (first) lcur[b] = lb;            // establish base at level start
#pragma unroll
            for (int j = 0; j < 6; ++j) momOut[b * 6 + j] = ub[j];
#pragma unroll
            for (int j = 0; j < 6; ++j) ttry[b * 6 + j] = sttry[j];
        }
    }
    __syncthreads();
    float th[6];
#pragma unroll
    for (int j = 0; j < 6; ++j) th[j] = sttry[j];
    eval_block<D, K3>(srcp, tgt, th, b, k, red);
    if (tid == 0) pB[(size_t)b * K3 + k] = red[0];
}

// ---------------------------------------------------------------------------
// Finalize: applies the very last trial decision (level 2, K3=32, n=262144)
// and writes theta-out + loss.
// ---------------------------------------------------------------------------
__global__ __launch_bounds__(256) void finalize_kernel(
    const float* __restrict__ theta0,
    const float* __restrict__ theta, const float* __restrict__ lcur,
    const int* __restrict__ active, const float* __restrict__ ttry,
    const double* __restrict__ pB, const float* __restrict__ lall,
    float* __restrict__ out)
{
    __shared__ double rs[8];
    __shared__ float fth[48];
    const int tid = threadIdx.x;
    const int r = tid >> 5, l = tid & 31;
    {
        double v = pB[r * 32 + l];
        v += __shfl_down(v, 16, 32);
        v += __shfl_down(v, 8, 32);
        v += __shfl_down(v, 4, 32);
        v += __shfl_down(v, 2, 32);
        v += __shfl_down(v, 1, 32);
        if (l == 0) rs[r] = v;
    }
    __syncthreads();
    if (tid < 8) {
        int b = tid;
        bool acc = false;
        if (active[b]) {
            float ln = (float)(rs[b] / 262144.0);
            acc = (ln + 1e-4f < lcur[b]);
        }
        for (int j = 0; j < 6; ++j)
            fth[b * 6 + j] = acc ? ttry[b * 6 + j] : theta[b * 6 + j];
    }
    __syncthreads();
    if (tid < 48) {
        int j = tid % 6;
        float d2r = (j < 3) ? PI180F : 1.0f;
        float td = fth[tid] * d2r;
        out[tid] = theta0[tid] + (td - theta0[tid]);
    } else if (tid < 56) {
        out[tid] = lall[tid - 48];
    }
}

// ---------------------------------------------------------------------------
// Pool: src-pool into padded layout, tgt-pool linear (round-6 verbatim).
// ---------------------------------------------------------------------------
template<int f>
__global__ void pool_pad_kernel(const float* __restrict__ src, const float* __restrict__ tgt,
                                float* __restrict__ srcp, float* __restrict__ tgtp)
{
    constexpr int Do = 64 / f;
    constexpr int P = Do + 3;
    constexpr int n = 8 * Do * Do * Do;
    int idx = blockIdx.x * blockDim.x + threadIdx.x;
    if (idx >= 2 * n) return;
    bool is_src = idx < n;
    int id = is_src ? idx : idx - n;
    int kk = id % Do;
    int jj = (id / Do) % Do;
    int ii = (id / (Do * Do)) % Do;
    int b  = id / (Do * Do * Do);
    const float* v = (is_src ? src : tgt) + (size_t)b * 262144;
    double s = 0.0;
    for (int p = 0; p < f; ++p)
        for (int q = 0; q < f; ++q)
            for (int r = 0; r < f; ++r)
                s += (double)v[((ii * f + p) * 64 + (jj * f + q)) * 64 + (kk * f + r)];
    float val = (float)(s / (double)(f * f * f));
    if (is_src) srcp[(size_t)b * P * P * P + (((ii + 1) * P + (jj + 1)) * P + (kk + 1))] = val;
    else        tgtp[id] = val;
}

// Copy D=64 src into padded layout (P=67).
__global__ void pad_copy_kernel(const float* __restrict__ src, float* __restrict__ dst)
{
    int idx = blockIdx.x * blockDim.x + threadIdx.x;
    if (idx >= 8 * 262144) return;
    int kk = idx & 63;
    int jj = (idx >> 6) & 63;
    int ii = (idx >> 12) & 63;
    int b  = idx >> 18;
    dst[(size_t)b * 67 * 67 * 67 + (((ii + 1) * 67 + (jj + 1)) * 67 + (kk + 1))] = src[idx];
}

__global__ void init_kernel(const float* __restrict__ theta_in,
                            float* __restrict__ theta_deg,
                            float* __restrict__ lcur,
                            int* __restrict__ active)
{
    int t = threadIdx.x;
    if (t < 48) {
        int j = t % 6;
        float d2r = (j < 3) ? PI180F : 1.0f;
        theta_deg[t] = theta_in[t] / d2r;
    }
    if (t < 8) { active[t] = 1; lcur[t] = 0.0f; }
}

// ---------------------------------------------------------------------------
template<int D, int K, int K3>
static void run_level(const float* srcp, const float* tgt,
                      float* const thetaS[2], float* const lcurS[2], int* const activeS[2],
                      float* const momS[2], float* ttry, float* lall,
                      double* pA, double* pB,
                      int L, int& scur, int& mcur, int k3prevLvl, int nprevLvl,
                      float ss0, hipStream_t stream)
{
    float ssv = ss0;
    for (int s = 0; s < 4; ++s) {
        for (int it = 0; it < 10; ++it) {
            int first = (s == 0 && it == 0) ? 1 : 0;
            int apply = !(L == 0 && first);
            int reset = (it == 0) ? 1 : 0;
            int k3p = first ? k3prevLvl : K3;
            int np  = first ? nprevLvl  : D * D * D;
            int nconf = first ? 13 : 12;
            int so = apply ? (scur ^ 1) : scur;
            fd_kernel<D, K><<<nconf * 8 * K, 256, 0, stream>>>(
                srcp, tgt,
                thetaS[scur], lcurS[scur], activeS[scur],
                thetaS[so], lcurS[so], activeS[so],
                ttry, pB, pA, ssv, first, apply, reset, k3p, np);
            if (apply) scur ^= 1;
            trial_kernel<D, K3, K><<<8 * K3, 256, 0, stream>>>(
                srcp, tgt,
                thetaS[scur], lcurS[scur], activeS[scur],
                momS[mcur], momS[mcur ^ 1], ttry, lall, pA, pB, ssv, first);
            mcur ^= 1;
        }
        ssv *= 0.5f;
    }
}

extern "C" void kernel_launch(void* const* d_in, const int* in_sizes, int n_in,
                              void* d_out, int out_size, void* d_ws, size_t ws_size,
                              hipStream_t stream)
{
    const float* theta0 = (const float*)d_in[0];
    const float* source = (const float*)d_in[1];
    const float* target = (const float*)d_in[2];
    float* out = (float*)d_out;

    char* ws = (char*)d_ws;
    size_t off = 0;
    auto alloc = [&](size_t bytes) -> void* {
        off = (off + 255) & ~(size_t)255;
        void* p = ws + off;
        off += bytes;
        return p;
    };
    float* thetaS[2] = { (float*)alloc(48 * 4), (float*)alloc(48 * 4) };
    float* lcurS[2]  = { (float*)alloc(8 * 4),  (float*)alloc(8 * 4)  };
    int*   activeS[2]= { (int*)alloc(8 * 4),    (int*)alloc(8 * 4)    };
    float* momS[2]   = { (float*)alloc(48 * 4), (float*)alloc(48 * 4) };
    float* ttry  = (float*)alloc(48 * 4);
    float* lall  = (float*)alloc(8 * 4);
    double* pA   = (double*)alloc(13 * 8 * 32 * 8);
    double* pB   = (double*)alloc(8 * 32 * 8);
    float* tgt2  = (float*)alloc((size_t)8 * 32768 * 4);
    float* tgt4  = (float*)alloc((size_t)8 * 4096 * 4);
    const size_t PS16 = 19 * 19 * 19, PS32 = 35 * 35 * 35, PS64 = 67 * 67 * 67;
    float* pad16 = (float*)alloc((size_t)8 * PS16 * 4);
    float* pad32 = (float*)alloc((size_t)8 * PS32 * 4);
    float* pad64 = (float*)alloc((size_t)8 * PS64 * 4);

    hipMemsetAsync(pad16, 0, (size_t)8 * PS16 * 4, stream);
    hipMemsetAsync(pad32, 0, (size_t)8 * PS32 * 4, stream);
    hipMemsetAsync(pad64, 0, (size_t)8 * PS64 * 4, stream);

    pool_pad_kernel<2><<<(2 * 8 * 32768 + 255) / 256, 256, 0, stream>>>(source, target, pad32, tgt2);
    pool_pad_kernel<4><<<(2 * 8 * 4096 + 255) / 256, 256, 0, stream>>>(source, target, pad16, tgt4);
    pad_copy_kernel<<<(8 * 262144 + 255) / 256, 256, 0, stream>>>(source, pad64);
    init_kernel<<<1, 64, 0, stream>>>(theta0, thetaS[0], lcurS[0], activeS[0]);

    int scur = 0, mcur = 0;
    run_level<16,  2, 16>(pad16, tgt4,   thetaS, lcurS, activeS, momS, ttry, lall,
                          pA, pB, 0, scur, mcur, 16, 4096, 8.0f, stream);
    run_level<32,  8, 32>(pad32, tgt2,   thetaS, lcurS, activeS, momS, ttry, lall,
                          pA, pB, 1, scur, mcur, 16, 4096, 4.0f, stream);
    run_level<64, 32, 32>(pad64, target, thetaS, lcurS, activeS, momS, ttry, lall,
                          pA, pB, 2, scur, mcur, 32, 32768, 2.0f, stream);

    finalize_kernel<<<1, 256, 0, stream>>>(
        theta0, thetaS[scur], lcurS[scur], activeS[scur],
        ttry, pB, lall, out);
}